// Round 1
// baseline (3195.310 us; speedup 1.0000x reference)
//
#include <hip/hip_runtime.h>
#include <math.h>

#define D_MODEL 1024
#define N_HEADS 16
#define D_HEAD 64
#define B_ 2
#define S_ 2048

// Generic C[M,N] = A[M,K] @ W[N,K]^T + bias[N], all fp32 row-major.
template<int BM, int BN, int BK, int TM, int TN>
__global__ __launch_bounds__(256)
void gemm_bias_kernel(const float* __restrict__ A,
                      const float* __restrict__ W,
                      const float* __restrict__ bias,
                      float* __restrict__ C,
                      int M, int N, int K) {
    __shared__ float As[BK][BM + 4];
    __shared__ float Ws[BK][BN + 4];
    const int t  = threadIdx.x;
    const int tx = t & 15;   // N direction
    const int ty = t >> 4;   // M direction
    const int m0 = blockIdx.y * BM;
    const int n0 = blockIdx.x * BN;

    float acc[TM][TN];
#pragma unroll
    for (int i = 0; i < TM; i++)
#pragma unroll
        for (int j = 0; j < TN; j++) acc[i][j] = 0.f;

    for (int k0 = 0; k0 < K; k0 += BK) {
        // Load A tile [BM][BK] -> As[k][m]
        for (int e = t; e < BM * BK; e += 256) {
            int kk = e & (BK - 1);
            int row = e / BK;
            As[kk][row] = A[(size_t)(m0 + row) * K + k0 + kk];
        }
        // Load W tile [BN][BK] -> Ws[k][n]
        for (int e = t; e < BN * BK; e += 256) {
            int kk = e & (BK - 1);
            int col = e / BK;
            Ws[kk][col] = W[(size_t)(n0 + col) * K + k0 + kk];
        }
        __syncthreads();
#pragma unroll
        for (int kk = 0; kk < BK; kk++) {
            float a[TM], b[TN];
#pragma unroll
            for (int i = 0; i < TM; i++) a[i] = As[kk][ty * TM + i];
#pragma unroll
            for (int j = 0; j < TN; j++) b[j] = Ws[kk][tx * TN + j];
#pragma unroll
            for (int i = 0; i < TM; i++)
#pragma unroll
                for (int j = 0; j < TN; j++) acc[i][j] += a[i] * b[j];
        }
        __syncthreads();
    }

#pragma unroll
    for (int i = 0; i < TM; i++) {
        int m = m0 + ty * TM + i;
#pragma unroll
        for (int j = 0; j < TN; j++) {
            int n = n0 + tx * TN + j;
            C[(size_t)m * N + n] = acc[i][j] + bias[n];
        }
    }
}

// Fused MQA attention. One block per (b, h, 16-query-row tile).
// Pass 1: scores + online (max, sumexp).  Pass 2: recompute scores, write
// normalized attn (exactly once), accumulate ctx = P @ V.
__global__ __launch_bounds__(256)
void mqa_attn_kernel(const float* __restrict__ Q,    // [B*S, 1024]
                     const float* __restrict__ Kp,   // [B*S, 64]
                     const float* __restrict__ Vp,   // [B*S, 64]
                     float* __restrict__ attn,       // [B,H,S,S]
                     float* __restrict__ ctx)        // [B*S, 1024]
{
    __shared__ float qs[16][D_HEAD];        // broadcast reads only
    __shared__ float ks[64][D_HEAD + 1];    // +1 pad: col reads by lane
    __shared__ float vs[64][D_HEAD + 1];
    __shared__ float ps[16][64 + 1];

    const int t    = threadIdx.x;
    const int lane = t & 63;
    const int w    = t >> 6;            // wave id 0..3 -> rows 4w..4w+3
    const int bid  = blockIdx.x;
    const int qt   = bid & 127;         // S/16 = 128 q-tiles
    const int h    = (bid >> 7) & 15;
    const int b    = bid >> 11;
    const int q0   = qt * 16;
    const float scale = 0.125f;         // 1/sqrt(64)

    // Load Q tile [16][64]
    for (int e = t; e < 16 * D_HEAD; e += 256) {
        int r = e >> 6, d = e & 63;
        qs[r][d] = Q[(size_t)(b * S_ + q0 + r) * D_MODEL + h * D_HEAD + d];
    }
    __syncthreads();

    float m[4], l[4];
#pragma unroll
    for (int rr = 0; rr < 4; rr++) { m[rr] = -1e30f; l[rr] = 0.f; }

    // ---- Pass 1: online max & sumexp ----
    for (int kt = 0; kt < S_; kt += 64) {
        for (int e = t; e < 64 * D_HEAD; e += 256) {
            int r = e >> 6, d = e & 63;
            ks[r][d] = Kp[(size_t)(b * S_ + kt + r) * D_HEAD + d];
        }
        __syncthreads();
        float s[4] = {0.f, 0.f, 0.f, 0.f};
#pragma unroll 8
        for (int dd = 0; dd < D_HEAD; dd++) {
            float kv = ks[lane][dd];
#pragma unroll
            for (int rr = 0; rr < 4; rr++) s[rr] += qs[w * 4 + rr][dd] * kv;
        }
#pragma unroll
        for (int rr = 0; rr < 4; rr++) {
            float sv = s[rr] * scale;
            float tm = sv;
            for (int off = 32; off; off >>= 1) tm = fmaxf(tm, __shfl_xor(tm, off));
            float mn = fmaxf(m[rr], tm);
            float e_ = __expf(sv - mn);
            float ts = e_;
            for (int off = 32; off; off >>= 1) ts += __shfl_xor(ts, off);
            l[rr] = l[rr] * __expf(m[rr] - mn) + ts;
            m[rr] = mn;
        }
        __syncthreads();
    }

    float inv_l[4];
#pragma unroll
    for (int rr = 0; rr < 4; rr++) inv_l[rr] = 1.f / l[rr];

    float cacc[4] = {0.f, 0.f, 0.f, 0.f};

    // ---- Pass 2: write attn, accumulate ctx ----
    for (int kt = 0; kt < S_; kt += 64) {
        for (int e = t; e < 64 * D_HEAD; e += 256) {
            int r = e >> 6, d = e & 63;
            size_t src = (size_t)(b * S_ + kt + r) * D_HEAD + d;
            ks[r][d] = Kp[src];
            vs[r][d] = Vp[src];
        }
        __syncthreads();
        float s[4] = {0.f, 0.f, 0.f, 0.f};
#pragma unroll 8
        for (int dd = 0; dd < D_HEAD; dd++) {
            float kv = ks[lane][dd];
#pragma unroll
            for (int rr = 0; rr < 4; rr++) s[rr] += qs[w * 4 + rr][dd] * kv;
        }
#pragma unroll
        for (int rr = 0; rr < 4; rr++) {
            int r = w * 4 + rr;
            float p = __expf(s[rr] * scale - m[rr]) * inv_l[rr];
            attn[((size_t)(b * N_HEADS + h) * S_ + (q0 + r)) * S_ + kt + lane] = p;
            ps[r][lane] = p;   // same wave reads its own rows: no barrier needed
        }
        // PV: thread owns (rows 4w..4w+3, d = lane)
#pragma unroll 8
        for (int c = 0; c < 64; c++) {
            float vv = vs[c][lane];
#pragma unroll
            for (int rr = 0; rr < 4; rr++) cacc[rr] += ps[w * 4 + rr][c] * vv;
        }
        __syncthreads();
    }

#pragma unroll
    for (int rr = 0; rr < 4; rr++) {
        int q = q0 + w * 4 + rr;
        ctx[(size_t)(b * S_ + q) * D_MODEL + h * D_HEAD + lane] = cacc[rr];
    }
}

extern "C" void kernel_launch(void* const* d_in, const int* in_sizes, int n_in,
                              void* d_out, int out_size, void* d_ws, size_t ws_size,
                              hipStream_t stream) {
    const float* query = (const float*)d_in[0];
    const float* key   = (const float*)d_in[1];
    const float* value = (const float*)d_in[2];
    const float* Wq_w  = (const float*)d_in[3];
    const float* Wq_b  = (const float*)d_in[4];
    const float* Wk_w  = (const float*)d_in[5];
    const float* Wk_b  = (const float*)d_in[6];
    const float* Wv_w  = (const float*)d_in[7];
    const float* Wv_b  = (const float*)d_in[8];
    const float* Wo_w  = (const float*)d_in[9];
    const float* Wo_b  = (const float*)d_in[10];

    // Workspace layout (fp32): Q[4096,1024] | K[4096,64] | V[4096,64] | ctx[4096,1024]
    // Total = 8,912,896 floats = 35.7 MB.
    float* Q   = (float*)d_ws;
    float* Kp  = Q  + (size_t)4096 * 1024;
    float* Vp  = Kp + (size_t)4096 * 64;
    float* ctx = Vp + (size_t)4096 * 64;

    float* out  = (float*)d_out;                       // [2,2048,1024]
    float* attn = out + (size_t)4096 * 1024;           // [2,16,2048,2048]

    dim3 blk(256);

    // Projections
    gemm_bias_kernel<128, 128, 16, 8, 8><<<dim3(8, 32), blk, 0, stream>>>(
        query, Wq_w, Wq_b, Q, 4096, 1024, 1024);
    gemm_bias_kernel<128, 64, 16, 8, 4><<<dim3(1, 32), blk, 0, stream>>>(
        key, Wk_w, Wk_b, Kp, 4096, 64, 1024);
    gemm_bias_kernel<128, 64, 16, 8, 4><<<dim3(1, 32), blk, 0, stream>>>(
        value, Wv_w, Wv_b, Vp, 4096, 64, 1024);

    // Fused attention: B*H*(S/16) = 2*16*128 = 4096 blocks
    mqa_attn_kernel<<<dim3(4096), blk, 0, stream>>>(Q, Kp, Vp, attn, ctx);

    // Output projection
    gemm_bias_kernel<128, 128, 16, 8, 8><<<dim3(8, 32), blk, 0, stream>>>(
        ctx, Wo_w, Wo_b, out, 4096, 1024, 1024);
}

// Round 2
// 502.267 us; speedup vs baseline: 6.3618x; 6.3618x over previous
//
#include <hip/hip_runtime.h>
#include <hip/hip_bf16.h>
#include <math.h>

#define D_MODEL 1024
#define N_HEADS 16
#define D_HEAD 64
#define S_ 2048

typedef __attribute__((ext_vector_type(8))) short short8;
typedef __attribute__((ext_vector_type(4))) float f32x4;

static __device__ inline short f2bf(float f) {
    union { __hip_bfloat16 h; short s; } u;
    u.h = __float2bfloat16(f);
    return u.s;
}

static __device__ inline f32x4 mfma16(short8 a, short8 b, f32x4 c) {
    return __builtin_amdgcn_mfma_f32_16x16x32_bf16(a, b, c, 0, 0, 0);
}

// C[M,N] = (A[M,K] @ W[N,K]^T + bias) * out_scale, bf16 MFMA, fp32 accum.
// A_BF16: A is bf16 (else fp32, converted during staging). W always fp32.
// OUT_MODE: 0 = fp32 row-major, 1 = bf16 row-major, 2 = bf16 transposed Vt[b][d][s].
template<int BM, int BN, int BK, int A_BF16, int OUT_MODE>
__global__ __launch_bounds__(256)
void mfma_gemm(const void* __restrict__ Av, const float* __restrict__ W,
               const float* __restrict__ bias, void* __restrict__ Cv,
               int M, int N, int K, float out_scale) {
    constexpr int PAD = 8;
    __shared__ short As[BM][BK + PAD];
    __shared__ short Bs[BN][BK + PAD];
    const int t = threadIdx.x;
    const int lane = t & 63;
    const int w = t >> 6;
    const int wr = w >> 1, wc = w & 1;
    const int m0 = blockIdx.y * BM;
    const int n0 = blockIdx.x * BN;
    const int r15 = lane & 15, g = lane >> 4;
    constexpr int NI = BM / 32;
    constexpr int NJ = BN / 32;
    constexpr int ACH = BK / 8;     // 8-elem chunks per row

    f32x4 acc[NI][NJ];
#pragma unroll
    for (int i = 0; i < NI; i++)
#pragma unroll
        for (int j = 0; j < NJ; j++) acc[i][j] = (f32x4){0.f, 0.f, 0.f, 0.f};

    for (int k0 = 0; k0 < K; k0 += BK) {
        for (int e = t; e < BM * ACH; e += 256) {
            int r = e / ACH, ck = e % ACH;
            short8 v;
            if (A_BF16) {
                v = *reinterpret_cast<const short8*>(
                    (const short*)Av + (size_t)(m0 + r) * K + k0 + ck * 8);
            } else {
                const float* src = (const float*)Av + (size_t)(m0 + r) * K + k0 + ck * 8;
#pragma unroll
                for (int j = 0; j < 8; j++) v[j] = f2bf(src[j]);
            }
            *reinterpret_cast<short8*>(&As[r][ck * 8]) = v;
        }
        for (int e = t; e < BN * ACH; e += 256) {
            int r = e / ACH, ck = e % ACH;
            const float* src = W + (size_t)(n0 + r) * K + k0 + ck * 8;
            short8 v;
#pragma unroll
            for (int j = 0; j < 8; j++) v[j] = f2bf(src[j]);
            *reinterpret_cast<short8*>(&Bs[r][ck * 8]) = v;
        }
        __syncthreads();
#pragma unroll
        for (int kc = 0; kc < BK / 32; kc++) {
            short8 af[NI], bw[NJ];
#pragma unroll
            for (int i = 0; i < NI; i++)
                af[i] = *reinterpret_cast<const short8*>(
                    &As[wr * 16 * NI + i * 16 + r15][kc * 32 + g * 8]);
#pragma unroll
            for (int j = 0; j < NJ; j++)
                bw[j] = *reinterpret_cast<const short8*>(
                    &Bs[wc * 16 * NJ + j * 16 + r15][kc * 32 + g * 8]);
#pragma unroll
            for (int i = 0; i < NI; i++)
#pragma unroll
                for (int j = 0; j < NJ; j++)
                    acc[i][j] = mfma16(af[i], bw[j], acc[i][j]);
        }
        __syncthreads();
    }

#pragma unroll
    for (int i = 0; i < NI; i++) {
#pragma unroll
        for (int j = 0; j < NJ; j++) {
            int ncol = n0 + wc * 16 * NJ + j * 16 + r15;
            float bv = bias[ncol];
#pragma unroll
            for (int reg = 0; reg < 4; reg++) {
                int mrow = m0 + wr * 16 * NI + i * 16 + g * 4 + reg;
                float val = (acc[i][j][reg] + bv) * out_scale;
                if (OUT_MODE == 0) {
                    ((float*)Cv)[(size_t)mrow * N + ncol] = val;
                } else if (OUT_MODE == 1) {
                    ((short*)Cv)[(size_t)mrow * N + ncol] = f2bf(val);
                } else {
                    // Vt[b][d=ncol][s], b = mrow>>11, s = mrow & 2047
                    ((short*)Cv)[((((size_t)(mrow >> 11)) * 64 + ncol) << 11) +
                                 (mrow & 2047)] = f2bf(val);
                }
            }
        }
    }
}

// Fused MQA attention, MFMA bf16. Block = (b, h, 64-q-row tile), 4 waves x 16 rows.
// Q is pre-scaled by 1/sqrt(64). No max subtraction (|s| <= ~10 << 88).
__global__ __launch_bounds__(256)
void mqa_attn_mfma(const short* __restrict__ Qb,   // [B*S][1024] bf16 (pre-scaled)
                   const short* __restrict__ Kb,   // [B*S][64]  bf16
                   const short* __restrict__ Vtb,  // [B][64][S] bf16
                   float* __restrict__ attn,       // [B][H][S][S] fp32
                   short* __restrict__ ctxb)       // [B*S][1024] bf16
{
    __shared__ short Qs[64][72];
    __shared__ short Ks[64][72];
    __shared__ short Vts[64][72];
    __shared__ short Ps[64][72];

    const int t = threadIdx.x, lane = t & 63, w = t >> 6;
    const int bid = blockIdx.x;
    const int qt = bid & 31;
    const int h  = (bid >> 5) & 15;
    const int b  = bid >> 9;
    const int q0 = qt * 64;
    const int r15 = lane & 15, g = lane >> 4;

    // Load Q tile [64 q][64 d]
    for (int e = t; e < 512; e += 256) {
        int r = e >> 3, ck = e & 7;
        *reinterpret_cast<short8*>(&Qs[r][ck * 8]) =
            *reinterpret_cast<const short8*>(
                Qb + (size_t)(b * S_ + q0 + r) * D_MODEL + h * D_HEAD + ck * 8);
    }
    __syncthreads();
    short8 aq0 = *reinterpret_cast<const short8*>(&Qs[w * 16 + r15][g * 8]);
    short8 aq1 = *reinterpret_cast<const short8*>(&Qs[w * 16 + r15][32 + g * 8]);

    // ---- Pass 1: row sums of exp(s) ----
    float lsum[4] = {0.f, 0.f, 0.f, 0.f};
    for (int kt = 0; kt < S_; kt += 64) {
        for (int e = t; e < 512; e += 256) {
            int r = e >> 3, ck = e & 7;
            *reinterpret_cast<short8*>(&Ks[r][ck * 8]) =
                *reinterpret_cast<const short8*>(
                    Kb + (size_t)(b * S_ + kt + r) * D_HEAD + ck * 8);
        }
        __syncthreads();
#pragma unroll
        for (int n = 0; n < 4; n++) {
            short8 bk0 = *reinterpret_cast<const short8*>(&Ks[n * 16 + r15][g * 8]);
            short8 bk1 = *reinterpret_cast<const short8*>(&Ks[n * 16 + r15][32 + g * 8]);
            f32x4 s = (f32x4){0.f, 0.f, 0.f, 0.f};
            s = mfma16(aq0, bk0, s);
            s = mfma16(aq1, bk1, s);
#pragma unroll
            for (int reg = 0; reg < 4; reg++) lsum[reg] += __expf(s[reg]);
        }
        __syncthreads();
    }
#pragma unroll
    for (int reg = 0; reg < 4; reg++) {
        float v = lsum[reg];
        v += __shfl_xor(v, 1); v += __shfl_xor(v, 2);
        v += __shfl_xor(v, 4); v += __shfl_xor(v, 8);
        lsum[reg] = 1.f / v;
    }

    // ---- Pass 2: recompute scores, write attn, accumulate PV ----
    f32x4 ctx_acc[4];
#pragma unroll
    for (int n = 0; n < 4; n++) ctx_acc[n] = (f32x4){0.f, 0.f, 0.f, 0.f};

    for (int kt = 0; kt < S_; kt += 64) {
        for (int e = t; e < 512; e += 256) {
            int r = e >> 3, ck = e & 7;
            *reinterpret_cast<short8*>(&Ks[r][ck * 8]) =
                *reinterpret_cast<const short8*>(
                    Kb + (size_t)(b * S_ + kt + r) * D_HEAD + ck * 8);
            *reinterpret_cast<short8*>(&Vts[r][ck * 8]) =
                *reinterpret_cast<const short8*>(
                    Vtb + (((size_t)(b * 64 + r)) << 11) + kt + ck * 8);
        }
        __syncthreads();

        size_t abase = ((size_t)((b * N_HEADS + h) * S_) + q0 + w * 16 + g * 4) * S_ + kt;
#pragma unroll
        for (int n = 0; n < 4; n++) {
            short8 bk0 = *reinterpret_cast<const short8*>(&Ks[n * 16 + r15][g * 8]);
            short8 bk1 = *reinterpret_cast<const short8*>(&Ks[n * 16 + r15][32 + g * 8]);
            f32x4 s = (f32x4){0.f, 0.f, 0.f, 0.f};
            s = mfma16(aq0, bk0, s);
            s = mfma16(aq1, bk1, s);
#pragma unroll
            for (int reg = 0; reg < 4; reg++) {
                float p = __expf(s[reg]) * lsum[reg];
                attn[abase + (size_t)reg * S_ + n * 16 + r15] = p;
                Ps[w * 16 + g * 4 + reg][n * 16 + r15] = f2bf(p);
            }
        }
        // Same-wave DS ordering: Ps written above is read below by the same wave.
        short8 ap0 = *reinterpret_cast<const short8*>(&Ps[w * 16 + r15][g * 8]);
        short8 ap1 = *reinterpret_cast<const short8*>(&Ps[w * 16 + r15][32 + g * 8]);
#pragma unroll
        for (int n = 0; n < 4; n++) {
            short8 bv0 = *reinterpret_cast<const short8*>(&Vts[n * 16 + r15][g * 8]);
            short8 bv1 = *reinterpret_cast<const short8*>(&Vts[n * 16 + r15][32 + g * 8]);
            ctx_acc[n] = mfma16(ap0, bv0, ctx_acc[n]);
            ctx_acc[n] = mfma16(ap1, bv1, ctx_acc[n]);
        }
        __syncthreads();
    }

#pragma unroll
    for (int n = 0; n < 4; n++) {
#pragma unroll
        for (int reg = 0; reg < 4; reg++) {
            int token = b * S_ + q0 + w * 16 + g * 4 + reg;
            ctxb[(size_t)token * D_MODEL + h * D_HEAD + n * 16 + r15] =
                f2bf(ctx_acc[n][reg]);
        }
    }
}

extern "C" void kernel_launch(void* const* d_in, const int* in_sizes, int n_in,
                              void* d_out, int out_size, void* d_ws, size_t ws_size,
                              hipStream_t stream) {
    const float* query = (const float*)d_in[0];
    const float* key   = (const float*)d_in[1];
    const float* value = (const float*)d_in[2];
    const float* Wq_w  = (const float*)d_in[3];
    const float* Wq_b  = (const float*)d_in[4];
    const float* Wk_w  = (const float*)d_in[5];
    const float* Wk_b  = (const float*)d_in[6];
    const float* Wv_w  = (const float*)d_in[7];
    const float* Wv_b  = (const float*)d_in[8];
    const float* Wo_w  = (const float*)d_in[9];
    const float* Wo_b  = (const float*)d_in[10];

    // Workspace (bf16 shorts): Qb[4096*1024] | Kb[4096*64] | Vtb[2*64*2048] | ctxb[4096*1024]
    short* Qb   = (short*)d_ws;
    short* Kb   = Qb  + (size_t)4096 * 1024;
    short* Vtb  = Kb  + (size_t)4096 * 64;
    short* ctxb = Vtb + (size_t)2 * 64 * 2048;

    float* out  = (float*)d_out;
    float* attn = out + (size_t)4096 * 1024;

    dim3 blk(256);

    // Q-proj -> bf16, pre-scaled by 1/sqrt(64)
    mfma_gemm<128, 128, 64, 0, 1><<<dim3(8, 32), blk, 0, stream>>>(
        query, Wq_w, Wq_b, Qb, 4096, 1024, 1024, 0.125f);
    // K-proj -> bf16 row-major
    mfma_gemm<128, 64, 64, 0, 1><<<dim3(1, 32), blk, 0, stream>>>(
        key, Wk_w, Wk_b, Kb, 4096, 64, 1024, 1.0f);
    // V-proj -> bf16 transposed Vt[b][d][s]
    mfma_gemm<128, 64, 64, 0, 2><<<dim3(1, 32), blk, 0, stream>>>(
        value, Wv_w, Wv_b, Vtb, 4096, 64, 1024, 1.0f);

    // Attention: B*H*(S/64) = 2*16*32 = 1024 blocks
    mqa_attn_mfma<<<dim3(1024), blk, 0, stream>>>(Qb, Kb, Vtb, attn, ctxb);

    // Out-proj: bf16 ctx @ Wo^T + bias -> fp32 out
    mfma_gemm<128, 128, 64, 1, 0><<<dim3(8, 32), blk, 0, stream>>>(
        ctxb, Wo_w, Wo_b, out, 4096, 1024, 1024, 1.0f);
}

// Round 3
// 431.037 us; speedup vs baseline: 7.4131x; 1.1653x over previous
//
#include <hip/hip_runtime.h>
#include <hip/hip_bf16.h>
#include <math.h>

#define D_MODEL 1024
#define N_HEADS 16
#define D_HEAD 64
#define S_ 2048

typedef __attribute__((ext_vector_type(8))) short short8;
typedef __attribute__((ext_vector_type(4))) float f32x4;

static __device__ inline short f2bf(float f) {
    union { __hip_bfloat16 h; short s; } u;
    u.h = __float2bfloat16(f);
    return u.s;
}

static __device__ inline f32x4 mfma16(short8 a, short8 b, f32x4 c) {
    return __builtin_amdgcn_mfma_f32_16x16x32_bf16(a, b, c, 0, 0, 0);
}

static __device__ inline void load_lds16(const void* g, void* l) {
    __builtin_amdgcn_global_load_lds(
        (const __attribute__((address_space(1))) unsigned int*)g,
        (__attribute__((address_space(3))) unsigned int*)l, 16, 0, 0);
}

// C[M,N] = (A[M,K] @ W[N,K]^T + bias) * out_scale, bf16 MFMA, fp32 accum.
// A_BF16: A is bf16 (else fp32, converted during staging). W always fp32.
// OUT_MODE: 0 = fp32 row-major, 1 = bf16 row-major, 2 = bf16 transposed Vt[b][d][s].
template<int BM, int BN, int BK, int A_BF16, int OUT_MODE>
__global__ __launch_bounds__(256)
void mfma_gemm(const void* __restrict__ Av, const float* __restrict__ W,
               const float* __restrict__ bias, void* __restrict__ Cv,
               int M, int N, int K, float out_scale) {
    constexpr int PAD = 8;
    __shared__ short As[BM][BK + PAD];
    __shared__ short Bs[BN][BK + PAD];
    const int t = threadIdx.x;
    const int lane = t & 63;
    const int w = t >> 6;
    const int wr = w >> 1, wc = w & 1;
    const int m0 = blockIdx.y * BM;
    const int n0 = blockIdx.x * BN;
    const int r15 = lane & 15, g = lane >> 4;
    constexpr int NI = BM / 32;
    constexpr int NJ = BN / 32;
    constexpr int ACH = BK / 8;

    f32x4 acc[NI][NJ];
#pragma unroll
    for (int i = 0; i < NI; i++)
#pragma unroll
        for (int j = 0; j < NJ; j++) acc[i][j] = (f32x4){0.f, 0.f, 0.f, 0.f};

    for (int k0 = 0; k0 < K; k0 += BK) {
        for (int e = t; e < BM * ACH; e += 256) {
            int r = e / ACH, ck = e % ACH;
            short8 v;
            if (A_BF16) {
                v = *reinterpret_cast<const short8*>(
                    (const short*)Av + (size_t)(m0 + r) * K + k0 + ck * 8);
            } else {
                const float* src = (const float*)Av + (size_t)(m0 + r) * K + k0 + ck * 8;
#pragma unroll
                for (int j = 0; j < 8; j++) v[j] = f2bf(src[j]);
            }
            *reinterpret_cast<short8*>(&As[r][ck * 8]) = v;
        }
        for (int e = t; e < BN * ACH; e += 256) {
            int r = e / ACH, ck = e % ACH;
            const float* src = W + (size_t)(n0 + r) * K + k0 + ck * 8;
            short8 v;
#pragma unroll
            for (int j = 0; j < 8; j++) v[j] = f2bf(src[j]);
            *reinterpret_cast<short8*>(&Bs[r][ck * 8]) = v;
        }
        __syncthreads();
#pragma unroll
        for (int kc = 0; kc < BK / 32; kc++) {
            short8 af[NI], bw[NJ];
#pragma unroll
            for (int i = 0; i < NI; i++)
                af[i] = *reinterpret_cast<const short8*>(
                    &As[wr * 16 * NI + i * 16 + r15][kc * 32 + g * 8]);
#pragma unroll
            for (int j = 0; j < NJ; j++)
                bw[j] = *reinterpret_cast<const short8*>(
                    &Bs[wc * 16 * NJ + j * 16 + r15][kc * 32 + g * 8]);
#pragma unroll
            for (int i = 0; i < NI; i++)
#pragma unroll
                for (int j = 0; j < NJ; j++)
                    acc[i][j] = mfma16(af[i], bw[j], acc[i][j]);
        }
        __syncthreads();
    }

#pragma unroll
    for (int i = 0; i < NI; i++) {
#pragma unroll
        for (int j = 0; j < NJ; j++) {
            int ncol = n0 + wc * 16 * NJ + j * 16 + r15;
            float bv = bias[ncol];
#pragma unroll
            for (int reg = 0; reg < 4; reg++) {
                int mrow = m0 + wr * 16 * NI + i * 16 + g * 4 + reg;
                float val = (acc[i][j][reg] + bv) * out_scale;
                if (OUT_MODE == 0) {
                    ((float*)Cv)[(size_t)mrow * N + ncol] = val;
                } else if (OUT_MODE == 1) {
                    ((short*)Cv)[(size_t)mrow * N + ncol] = f2bf(val);
                } else {
                    ((short*)Cv)[((((size_t)(mrow >> 11)) * 64 + ncol) << 11) +
                                 (mrow & 2047)] = f2bf(val);
                }
            }
        }
    }
}

// Fused MQA attention v2. Block = (b, h, 128-q-row tile), 4 waves x 32 q-rows.
// Q pre-scaled by log2e/sqrt(64); exp2. Double-buffered K/V via global_load_lds
// with XOR-swizzle (linear dest + pre-swizzled source + swizzled ds_read).
__global__ __launch_bounds__(256)
void mqa_attn_mfma2(const short* __restrict__ Qb,   // [B*S][1024] bf16 (pre-scaled)
                    const short* __restrict__ Kb,   // [B*S][64]  bf16
                    const short* __restrict__ Vtb,  // [B][64][S] bf16
                    float* __restrict__ attn,       // [B][H][S][S] fp32
                    short* __restrict__ ctxb)       // [B*S][1024] bf16
{
    __shared__ short KB[2][64 * 64];   // linear [row][64] per buffer, swizzled content
    __shared__ short VB[2][64 * 64];
    __shared__ short Ps[128][72];

    const int t = threadIdx.x, lane = t & 63, w = t >> 6;
    const int bid = blockIdx.x;
    const int qt = bid & 15;
    const int h  = (bid >> 4) & 15;
    const int b  = bid >> 8;
    const int q0 = qt * 128;
    const int r15 = lane & 15, g = lane >> 4;

    // ---- Q fragments direct from global (rows = q0 + w*32 + qg*16 + r15) ----
    short8 aq[2][2];
#pragma unroll
    for (int qg = 0; qg < 2; qg++)
#pragma unroll
        for (int hf = 0; hf < 2; hf++)
            aq[qg][hf] = *reinterpret_cast<const short8*>(
                Qb + (size_t)(b * S_ + q0 + w * 32 + qg * 16 + r15) * D_MODEL +
                h * D_HEAD + hf * 32 + g * 8);

    // ---- Staging geometry (per-thread constants) ----
    // Tile = 64 rows x 128 bytes. Two 4KB chunks per tile (256 threads x 16B each).
    const int l0 = t * 16;            // chunk-0 linear byte in tile
    const int l1 = l0 + 4096;         // chunk-1
    const int row0 = l0 >> 7, row1 = l1 >> 7;
    const int ko0 = l0 ^ ((row0 & 7) << 4);               // K src byte (contiguous tile)
    const int ko1 = l1 ^ ((row1 & 7) << 4);
    const int vc0 = (l0 & 127) ^ ((row0 & 7) << 4);       // V col byte within row
    const int vc1 = (l1 & 127) ^ ((row1 & 7) << 4);
    const char* ktile0 = (const char*)(Kb + (size_t)b * S_ * D_HEAD);  // + kti*8192
    const char* vrow0 = (const char*)(Vtb + (((size_t)(b * 64 + row0)) << 11)) + vc0;
    const char* vrow1 = (const char*)(Vtb + (((size_t)(b * 64 + row1)) << 11)) + vc1;

#define STAGE_K(kti, buf) {                                                   \
        const char* kb_ = ktile0 + (size_t)(kti) * 8192;                      \
        load_lds16(kb_ + ko0, (char*)KB + (buf) * 8192 + w * 1024);           \
        load_lds16(kb_ + ko1, (char*)KB + (buf) * 8192 + 4096 + w * 1024); }
#define STAGE_V(kti, buf) {                                                   \
        load_lds16(vrow0 + (size_t)(kti) * 128, (char*)VB + (buf) * 8192 + w * 1024); \
        load_lds16(vrow1 + (size_t)(kti) * 128, (char*)VB + (buf) * 8192 + 4096 + w * 1024); }
    // swizzled fragment read: logical (row r, col-byte c) of a linear tile
#define FRAG(tile, r, c) (*reinterpret_cast<const short8*>(                   \
        (const char*)(tile) + ((r) << 7) + ((c) ^ (((r) & 7) << 4))))

    // ---- Pass 1: row sums of exp2(s) ----
    float lsum[2][4];
#pragma unroll
    for (int qg = 0; qg < 2; qg++)
#pragma unroll
        for (int reg = 0; reg < 4; reg++) lsum[qg][reg] = 0.f;

    int cur = 0;
    STAGE_K(0, 0);
    __syncthreads();
    for (int kti = 0; kti < 32; kti++) {
        if (kti + 1 < 32) STAGE_K(kti + 1, cur ^ 1);
        short8 kf[4][2];
#pragma unroll
        for (int n = 0; n < 4; n++)
#pragma unroll
            for (int hf = 0; hf < 2; hf++)
                kf[n][hf] = FRAG(&KB[cur][0], n * 16 + r15, hf * 64 + g * 16);
#pragma unroll
        for (int qg = 0; qg < 2; qg++)
#pragma unroll
            for (int n = 0; n < 4; n++) {
                f32x4 s = (f32x4){0.f, 0.f, 0.f, 0.f};
                s = mfma16(aq[qg][0], kf[n][0], s);
                s = mfma16(aq[qg][1], kf[n][1], s);
#pragma unroll
                for (int reg = 0; reg < 4; reg++) lsum[qg][reg] += exp2f(s[reg]);
            }
        __syncthreads();
        cur ^= 1;
    }

    float inv[2][4];
#pragma unroll
    for (int qg = 0; qg < 2; qg++)
#pragma unroll
        for (int reg = 0; reg < 4; reg++) {
            float v = lsum[qg][reg];
            v += __shfl_xor(v, 1); v += __shfl_xor(v, 2);
            v += __shfl_xor(v, 4); v += __shfl_xor(v, 8);
            inv[qg][reg] = 1.f / v;
        }

    // ---- Pass 2: recompute, write attn, accumulate PV ----
    f32x4 ctx[2][4];
#pragma unroll
    for (int qg = 0; qg < 2; qg++)
#pragma unroll
        for (int n = 0; n < 4; n++) ctx[qg][n] = (f32x4){0.f, 0.f, 0.f, 0.f};

    cur = 0;
    STAGE_K(0, 0);
    STAGE_V(0, 0);
    __syncthreads();
    for (int kti = 0; kti < 32; kti++) {
        if (kti + 1 < 32) { STAGE_K(kti + 1, cur ^ 1); STAGE_V(kti + 1, cur ^ 1); }
        short8 kf[4][2];
#pragma unroll
        for (int n = 0; n < 4; n++)
#pragma unroll
            for (int hf = 0; hf < 2; hf++)
                kf[n][hf] = FRAG(&KB[cur][0], n * 16 + r15, hf * 64 + g * 16);

#pragma unroll
        for (int qg = 0; qg < 2; qg++) {
            size_t abase = ((size_t)((b * N_HEADS + h) * S_) + q0 + w * 32 +
                            qg * 16 + g * 4) * S_ + kti * 64;
#pragma unroll
            for (int n = 0; n < 4; n++) {
                f32x4 s = (f32x4){0.f, 0.f, 0.f, 0.f};
                s = mfma16(aq[qg][0], kf[n][0], s);
                s = mfma16(aq[qg][1], kf[n][1], s);
#pragma unroll
                for (int reg = 0; reg < 4; reg++) {
                    float p = exp2f(s[reg]) * inv[qg][reg];
                    attn[abase + (size_t)reg * S_ + n * 16 + r15] = p;
                    Ps[w * 32 + qg * 16 + g * 4 + reg][n * 16 + r15] = f2bf(p);
                }
            }
        }
        // Same-wave write->read of Ps rows (w*32..w*32+31): no barrier needed.
        short8 ap[2][2], vf[4][2];
#pragma unroll
        for (int qg = 0; qg < 2; qg++)
#pragma unroll
            for (int hf = 0; hf < 2; hf++)
                ap[qg][hf] = *reinterpret_cast<const short8*>(
                    &Ps[w * 32 + qg * 16 + r15][hf * 32 + g * 8]);
#pragma unroll
        for (int n = 0; n < 4; n++)
#pragma unroll
            for (int hf = 0; hf < 2; hf++)
                vf[n][hf] = FRAG(&VB[cur][0], n * 16 + r15, hf * 64 + g * 16);
#pragma unroll
        for (int qg = 0; qg < 2; qg++)
#pragma unroll
            for (int n = 0; n < 4; n++) {
                ctx[qg][n] = mfma16(ap[qg][0], vf[n][0], ctx[qg][n]);
                ctx[qg][n] = mfma16(ap[qg][1], vf[n][1], ctx[qg][n]);
            }
        __syncthreads();
        cur ^= 1;
    }

#pragma unroll
    for (int qg = 0; qg < 2; qg++)
#pragma unroll
        for (int n = 0; n < 4; n++)
#pragma unroll
            for (int reg = 0; reg < 4; reg++) {
                int token = b * S_ + q0 + w * 32 + qg * 16 + g * 4 + reg;
                ctxb[(size_t)token * D_MODEL + h * D_HEAD + n * 16 + r15] =
                    f2bf(ctx[qg][n][reg]);
            }
#undef STAGE_K
#undef STAGE_V
#undef FRAG
}

extern "C" void kernel_launch(void* const* d_in, const int* in_sizes, int n_in,
                              void* d_out, int out_size, void* d_ws, size_t ws_size,
                              hipStream_t stream) {
    const float* query = (const float*)d_in[0];
    const float* key   = (const float*)d_in[1];
    const float* value = (const float*)d_in[2];
    const float* Wq_w  = (const float*)d_in[3];
    const float* Wq_b  = (const float*)d_in[4];
    const float* Wk_w  = (const float*)d_in[5];
    const float* Wk_b  = (const float*)d_in[6];
    const float* Wv_w  = (const float*)d_in[7];
    const float* Wv_b  = (const float*)d_in[8];
    const float* Wo_w  = (const float*)d_in[9];
    const float* Wo_b  = (const float*)d_in[10];

    short* Qb   = (short*)d_ws;
    short* Kb   = Qb  + (size_t)4096 * 1024;
    short* Vtb  = Kb  + (size_t)4096 * 64;
    short* ctxb = Vtb + (size_t)2 * 64 * 2048;

    float* out  = (float*)d_out;
    float* attn = out + (size_t)4096 * 1024;

    dim3 blk(256);

    // Q-proj -> bf16, pre-scaled by log2e/sqrt(64)
    mfma_gemm<128, 128, 64, 0, 1><<<dim3(8, 32), blk, 0, stream>>>(
        query, Wq_w, Wq_b, Qb, 4096, 1024, 1024, 0.125f * 1.44269504089f);
    // K-proj -> bf16 row-major (BM=64: 64 blocks)
    mfma_gemm<64, 64, 64, 0, 1><<<dim3(1, 64), blk, 0, stream>>>(
        key, Wk_w, Wk_b, Kb, 4096, 64, 1024, 1.0f);
    // V-proj -> bf16 transposed Vt[b][d][s]
    mfma_gemm<64, 64, 64, 0, 2><<<dim3(1, 64), blk, 0, stream>>>(
        value, Wv_w, Wv_b, Vtb, 4096, 64, 1024, 1.0f);

    // Attention: B*H*(S/128) = 2*16*16 = 512 blocks
    mqa_attn_mfma2<<<dim3(512), blk, 0, stream>>>(Qb, Kb, Vtb, attn, ctxb);

    // Out-proj: bf16 ctx @ Wo^T + bias -> fp32 out
    mfma_gemm<128, 128, 64, 1, 0><<<dim3(8, 32), blk, 0, stream>>>(
        ctxb, Wo_w, Wo_b, out, 4096, 1024, 1024, 1.0f);
}

// Round 4
// 224.118 us; speedup vs baseline: 14.2573x; 1.9233x over previous
//
#include <hip/hip_runtime.h>
#include <hip/hip_bf16.h>
#include <math.h>

#define D_MODEL 1024
#define N_HEADS 16
#define D_HEAD 64
#define S_ 2048

typedef __attribute__((ext_vector_type(8))) short short8;
typedef __attribute__((ext_vector_type(4))) float f32x4;
typedef __attribute__((ext_vector_type(16))) float f32x16;

static __device__ inline short f2bf(float f) {
    union { __hip_bfloat16 h; short s; } u;
    u.h = __float2bfloat16(f);
    return u.s;
}

static __device__ inline f32x4 mfma16(short8 a, short8 b, f32x4 c) {
    return __builtin_amdgcn_mfma_f32_16x16x32_bf16(a, b, c, 0, 0, 0);
}
static __device__ inline f32x16 mfma32(short8 a, short8 b, f32x16 c) {
    return __builtin_amdgcn_mfma_f32_32x32x16_bf16(a, b, c, 0, 0, 0);
}
static __device__ inline f32x16 zero16() {
    f32x16 z;
#pragma unroll
    for (int i = 0; i < 16; i++) z[i] = 0.f;
    return z;
}

static __device__ inline void load_lds16(const void* g, void* l) {
    __builtin_amdgcn_global_load_lds(
        (const __attribute__((address_space(1))) unsigned int*)g,
        (__attribute__((address_space(3))) unsigned int*)l, 16, 0, 0);
}

// ---------------- fp32 -> bf16 preconversion (inputs + weights) ----------------
__global__ __launch_bounds__(256)
void cvt_all(const float* __restrict__ q, const float* __restrict__ k,
             const float* __restrict__ v, const float* __restrict__ wq,
             const float* __restrict__ wk, const float* __restrict__ wv,
             const float* __restrict__ wo,
             short* dq, short* dk, short* dv, short* dwq, short* dwk,
             short* dwv, short* dwo) {
    size_t c = (size_t)blockIdx.x * 256 + threadIdx.x;   // 8-elem chunk id
    const float* s; short* d; size_t off;
    if (c < 524288)        { s = q;  d = dq;  off = c; }
    else if (c < 1048576)  { s = k;  d = dk;  off = c - 524288; }
    else if (c < 1572864)  { s = v;  d = dv;  off = c - 1048576; }
    else if (c < 1703936)  { s = wq; d = dwq; off = c - 1572864; }
    else if (c < 1712128)  { s = wk; d = dwk; off = c - 1703936; }
    else if (c < 1720320)  { s = wv; d = dwv; off = c - 1712128; }
    else                   { s = wo; d = dwo; off = c - 1720320; }
    const f32x4* sp = (const f32x4*)(s + off * 8);
    f32x4 a = sp[0], b = sp[1];
    short8 o;
    o[0] = f2bf(a[0]); o[1] = f2bf(a[1]); o[2] = f2bf(a[2]); o[3] = f2bf(a[3]);
    o[4] = f2bf(b[0]); o[5] = f2bf(b[1]); o[6] = f2bf(b[2]); o[7] = f2bf(b[3]);
    *(short8*)(d + off * 8) = o;
}

// ---------------- bf16 MFMA GEMM: C = (A @ W^T + bias) * scale ----------------
// A[M,K] bf16, W[N,K] bf16. global_load_lds staging, XOR-swizzled LDS, dbuf.
// OUT_MODE: 0 fp32 row-major (nt), 1 bf16 row-major, 2 bf16 transposed Vt[b][d][s].
template<int BM, int BN, int OUT_MODE>
__device__ __forceinline__ void gemm_body(
    const short* __restrict__ A, const short* __restrict__ Wb,
    const float* __restrict__ bias, void* __restrict__ Cv,
    int bx, int by, int M, int N, int K, float out_scale, char* lds)
{
    constexpr int NI = BM / 32, NJ = BN / 32;
    constexpr int AISS = BM / 32, WISS = BN / 32;
    char* As = lds;                       // [2][BM*128]
    char* Ws = lds + 2 * BM * 128;        // [2][BN*128]
    const int t = threadIdx.x, lane = t & 63, w = t >> 6;
    const int wr = w >> 1, wc = w & 1, r15 = lane & 15, g = lane >> 4;
    const int m0 = by * BM, n0 = bx * BN;
    const size_t Kb2 = (size_t)K * 2;

    int aR[AISS], aC[AISS];
#pragma unroll
    for (int i = 0; i < AISS; i++) {
        int l = i * 4096 + t * 16;
        aR[i] = l >> 7;
        aC[i] = (l & 127) ^ (((l >> 7) & 7) << 4);
    }

    f32x4 acc[NI][NJ];
#pragma unroll
    for (int i = 0; i < NI; i++)
#pragma unroll
        for (int j = 0; j < NJ; j++) acc[i][j] = (f32x4){0.f, 0.f, 0.f, 0.f};

    const int nk = K / 64;
    auto stage = [&](int kt, int buf) {
        size_t kb = (size_t)kt * 128;
#pragma unroll
        for (int i = 0; i < AISS; i++)
            load_lds16((const char*)A + (size_t)(m0 + aR[i]) * Kb2 + kb + aC[i],
                       As + buf * (BM * 128) + i * 4096 + (w << 10));
#pragma unroll
        for (int i = 0; i < WISS; i++)
            load_lds16((const char*)Wb + (size_t)(n0 + aR[i]) * Kb2 + kb + aC[i],
                       Ws + buf * (BN * 128) + i * 4096 + (w << 10));
    };

    stage(0, 0);
    __syncthreads();
    int cur = 0;
    for (int kt = 0; kt < nk; kt++) {
        if (kt + 1 < nk) stage(kt + 1, cur ^ 1);
        const char* Ab = As + cur * (BM * 128);
        const char* Wbs = Ws + cur * (BN * 128);
#pragma unroll
        for (int kc = 0; kc < 2; kc++) {
            short8 af[NI], bw[NJ];
#pragma unroll
            for (int i = 0; i < NI; i++) {
                int r = wr * (16 * NI) + i * 16 + r15;
                af[i] = *(const short8*)(Ab + r * 128 + ((kc * 64 + g * 16) ^ ((r & 7) << 4)));
            }
#pragma unroll
            for (int j = 0; j < NJ; j++) {
                int r = wc * (16 * NJ) + j * 16 + r15;
                bw[j] = *(const short8*)(Wbs + r * 128 + ((kc * 64 + g * 16) ^ ((r & 7) << 4)));
            }
#pragma unroll
            for (int i = 0; i < NI; i++)
#pragma unroll
                for (int j = 0; j < NJ; j++)
                    acc[i][j] = mfma16(af[i], bw[j], acc[i][j]);
        }
        __syncthreads();
        cur ^= 1;
    }

#pragma unroll
    for (int i = 0; i < NI; i++) {
#pragma unroll
        for (int j = 0; j < NJ; j++) {
            int ncol = n0 + wc * (16 * NJ) + j * 16 + r15;
            float bv = bias[ncol];
#pragma unroll
            for (int reg = 0; reg < 4; reg++) {
                int mrow = m0 + wr * (16 * NI) + i * 16 + g * 4 + reg;
                float val = (acc[i][j][reg] + bv) * out_scale;
                if (OUT_MODE == 0) {
                    __builtin_nontemporal_store(val, (float*)Cv + (size_t)mrow * N + ncol);
                } else if (OUT_MODE == 1) {
                    ((short*)Cv)[(size_t)mrow * N + ncol] = f2bf(val);
                } else {
                    ((short*)Cv)[((((size_t)(mrow >> 11)) * 64 + ncol) << 11) +
                                 (mrow & 2047)] = f2bf(val);
                }
            }
        }
    }
}

__global__ __launch_bounds__(256)
void qkv_proj(const short* __restrict__ qin, const short* __restrict__ kin,
              const short* __restrict__ vin, const short* __restrict__ wqb,
              const short* __restrict__ wkb, const short* __restrict__ wvb,
              const float* __restrict__ bq, const float* __restrict__ bk,
              const float* __restrict__ bv,
              short* Qb, short* Kb, short* Vtb) {
    __shared__ char lds[65536];
    int bid = blockIdx.x;
    if (bid < 256)
        gemm_body<128, 128, 1>(qin, wqb, bq, Qb, bid & 7, bid >> 3,
                               4096, 1024, 1024, 0.18033688011112f, lds); // (1/8)*log2(e)
    else if (bid < 288)
        gemm_body<128, 64, 1>(kin, wkb, bk, Kb, 0, bid - 256,
                              4096, 64, 1024, 1.0f, lds);
    else
        gemm_body<128, 64, 2>(vin, wvb, bv, Vtb, 0, bid - 288,
                              4096, 64, 1024, 1.0f, lds);
}

__global__ __launch_bounds__(256)
void o_proj(const short* __restrict__ ctxb, const short* __restrict__ wob,
            const float* __restrict__ bo, float* __restrict__ out) {
    __shared__ char lds[65536];
    gemm_body<128, 128, 0>(ctxb, wob, bo, out, blockIdx.x & 7, blockIdx.x >> 3,
                           4096, 1024, 1024, 1.0f, lds);
}

// ---------------- Fused MQA attention v3: 32x32x16 MFMA, nt stores ----------------
// Block = (b, h, 128-q tile), 4 waves x 32 q-rows. Q pre-scaled by log2e/8, exp2.
__global__ __launch_bounds__(256)
void mqa_attn3(const short* __restrict__ Qb,   // [B*S][1024] bf16 (pre-scaled)
               const short* __restrict__ Kb,   // [B*S][64]  bf16
               const short* __restrict__ Vtb,  // [B][64][S] bf16
               float* __restrict__ attn,       // [B][H][S][S] fp32
               short* __restrict__ ctxb)       // [B*S][1024] bf16
{
    __shared__ short KB2[2][64 * 64];
    __shared__ short VB2[2][64 * 64];
    __shared__ short Ps[128 * 64];

    const int t = threadIdx.x, lane = t & 63, w = t >> 6;
    const int l31 = lane & 31, h5 = lane >> 5;
    const int bid = blockIdx.x;
    const int qt = bid & 15, h = (bid >> 4) & 15, b = bid >> 8;
    const int q0 = qt * 128;
    const int wq = w * 32;

    // Q A-fragments (32x32x16: lane row = l31, k = kc*16 + h5*8 + j)
    short8 aq[4];
    {
        const char* qbase = (const char*)(Qb +
            (size_t)(b * S_ + q0 + wq + l31) * D_MODEL + h * 64);
#pragma unroll
        for (int kc = 0; kc < 4; kc++)
            aq[kc] = *(const short8*)(qbase + kc * 32 + h5 * 16);
    }

    // staging geometry (linear LDS dest + inverse-swizzled global source)
    const int l0 = t * 16, l1 = l0 + 4096;
    const int row0 = l0 >> 7, row1 = l1 >> 7;
    const int ko0 = l0 ^ ((row0 & 7) << 4);
    const int ko1 = l1 ^ ((row1 & 7) << 4);
    const int vc0 = (l0 & 127) ^ ((row0 & 7) << 4);
    const int vc1 = (l1 & 127) ^ ((row1 & 7) << 4);
    const char* ktile0 = (const char*)(Kb + (size_t)b * S_ * 64);
    const char* vrow0 = (const char*)(Vtb + (((size_t)(b * 64 + row0)) << 11)) + vc0;
    const char* vrow1 = (const char*)(Vtb + (((size_t)(b * 64 + row1)) << 11)) + vc1;

#define STAGE_K(kti, buf) {                                                    \
        const char* kb_ = ktile0 + (size_t)(kti) * 8192;                       \
        load_lds16(kb_ + ko0, (char*)KB2 + (buf) * 8192 + (w << 10));          \
        load_lds16(kb_ + ko1, (char*)KB2 + (buf) * 8192 + 4096 + (w << 10)); }
#define STAGE_V(kti, buf) {                                                    \
        load_lds16(vrow0 + (size_t)(kti) * 128, (char*)VB2 + (buf) * 8192 + (w << 10)); \
        load_lds16(vrow1 + (size_t)(kti) * 128, (char*)VB2 + (buf) * 8192 + 4096 + (w << 10)); }
#define RD(base, r, cb) (*(const short8*)((const char*)(base) + (r) * 128 + ((cb) ^ (((r) & 7) << 4))))

    // ---- Pass 1: row sums of exp2(s) ----
    float lsum[16];
#pragma unroll
    for (int reg = 0; reg < 16; reg++) lsum[reg] = 0.f;

    int cur = 0;
    STAGE_K(0, 0);
    __syncthreads();
    for (int kti = 0; kti < 32; kti++) {
        if (kti + 1 < 32) STAGE_K(kti + 1, cur ^ 1);
        f32x16 s0 = zero16(), s1 = zero16();
#pragma unroll
        for (int kc = 0; kc < 4; kc++) {
            short8 k0 = RD(KB2[cur], l31, kc * 32 + h5 * 16);
            s0 = mfma32(aq[kc], k0, s0);
            short8 k1 = RD(KB2[cur], 32 + l31, kc * 32 + h5 * 16);
            s1 = mfma32(aq[kc], k1, s1);
        }
#pragma unroll
        for (int reg = 0; reg < 16; reg++)
            lsum[reg] += exp2f(s0[reg]) + exp2f(s1[reg]);
        __syncthreads();
        cur ^= 1;
    }

    float inv[16];
#pragma unroll
    for (int reg = 0; reg < 16; reg++) {
        float v = lsum[reg];
        v += __shfl_xor(v, 1); v += __shfl_xor(v, 2);
        v += __shfl_xor(v, 4); v += __shfl_xor(v, 8); v += __shfl_xor(v, 16);
        inv[reg] = 1.f / v;
    }

    // ---- Pass 2: recompute, nt-store attn, accumulate PV ----
    f32x16 ctxA = zero16(), ctxB = zero16();
    float* attn_base = attn +
        (((size_t)((b * 16 + h) * 2048 + q0 + wq + 4 * h5)) << 11) + l31;

    cur = 0;
    STAGE_K(0, 0);
    STAGE_V(0, 0);
    __syncthreads();
    for (int kti = 0; kti < 32; kti++) {
        if (kti + 1 < 32) { STAGE_K(kti + 1, cur ^ 1); STAGE_V(kti + 1, cur ^ 1); }
        f32x16 s0 = zero16(), s1 = zero16();
#pragma unroll
        for (int kc = 0; kc < 4; kc++) {
            short8 k0 = RD(KB2[cur], l31, kc * 32 + h5 * 16);
            s0 = mfma32(aq[kc], k0, s0);
            short8 k1 = RD(KB2[cur], 32 + l31, kc * 32 + h5 * 16);
            s1 = mfma32(aq[kc], k1, s1);
        }
        float* arowptr = attn_base + (size_t)kti * 64;
#pragma unroll
        for (int reg = 0; reg < 16; reg++) {
            const int rloc = (reg & 3) + 8 * (reg >> 2);
            const int rps = wq + rloc + 4 * h5;
            float p0 = exp2f(s0[reg]) * inv[reg];
            __builtin_nontemporal_store(p0, arowptr + ((size_t)rloc << 11));
            *(short*)((char*)Ps + rps * 128 + ((l31 * 2) ^ ((rps & 7) << 4))) = f2bf(p0);
            float p1 = exp2f(s1[reg]) * inv[reg];
            __builtin_nontemporal_store(p1, arowptr + ((size_t)rloc << 11) + 32);
            *(short*)((char*)Ps + rps * 128 + ((64 + l31 * 2) ^ ((rps & 7) << 4))) = f2bf(p1);
        }
        // PV (same-wave DS order: Ps rows wq..wq+31 written above by this wave)
        short8 ap[4];
#pragma unroll
        for (int kc = 0; kc < 4; kc++)
            ap[kc] = RD(Ps, wq + l31, kc * 32 + h5 * 16);
#pragma unroll
        for (int kc = 0; kc < 4; kc++) {
            short8 v0 = RD(VB2[cur], l31, kc * 32 + h5 * 16);
            ctxA = mfma32(ap[kc], v0, ctxA);
            short8 v1 = RD(VB2[cur], 32 + l31, kc * 32 + h5 * 16);
            ctxB = mfma32(ap[kc], v1, ctxB);
        }
        __syncthreads();
        cur ^= 1;
    }

    const int tokbase = b * 2048 + q0 + wq + 4 * h5;
#pragma unroll
    for (int reg = 0; reg < 16; reg++) {
        const int rloc = (reg & 3) + 8 * (reg >> 2);
        size_t base = (size_t)(tokbase + rloc) * D_MODEL + h * 64 + l31;
        ctxb[base]      = f2bf(ctxA[reg]);
        ctxb[base + 32] = f2bf(ctxB[reg]);
    }
#undef STAGE_K
#undef STAGE_V
#undef RD
}

extern "C" void kernel_launch(void* const* d_in, const int* in_sizes, int n_in,
                              void* d_out, int out_size, void* d_ws, size_t ws_size,
                              hipStream_t stream) {
    const float* query = (const float*)d_in[0];
    const float* key   = (const float*)d_in[1];
    const float* value = (const float*)d_in[2];
    const float* Wq_w  = (const float*)d_in[3];
    const float* Wq_b  = (const float*)d_in[4];
    const float* Wk_w  = (const float*)d_in[5];
    const float* Wk_b  = (const float*)d_in[6];
    const float* Wv_w  = (const float*)d_in[7];
    const float* Wv_b  = (const float*)d_in[8];
    const float* Wo_w  = (const float*)d_in[9];
    const float* Wo_b  = (const float*)d_in[10];

    short* ws   = (short*)d_ws;
    short* qin  = ws;
    short* kin  = qin  + (size_t)4194304;
    short* vin  = kin  + (size_t)4194304;
    short* wqb  = vin  + (size_t)4194304;
    short* wkb  = wqb  + (size_t)1048576;
    short* wvb  = wkb  + (size_t)65536;
    short* wob  = wvb  + (size_t)65536;
    short* Qb   = wob  + (size_t)1048576;
    short* Kb   = Qb   + (size_t)4194304;
    short* Vtb  = Kb   + (size_t)262144;
    short* ctxb = Vtb  + (size_t)262144;

    float* out  = (float*)d_out;
    float* attn = out + (size_t)4096 * 1024;

    dim3 blk(256);

    cvt_all<<<dim3(7232), blk, 0, stream>>>(query, key, value, Wq_w, Wk_w, Wv_w,
                                            Wo_w, qin, kin, vin, wqb, wkb, wvb, wob);
    qkv_proj<<<dim3(320), blk, 0, stream>>>(qin, kin, vin, wqb, wkb, wvb,
                                            Wq_b, Wk_b, Wv_b, Qb, Kb, Vtb);
    mqa_attn3<<<dim3(512), blk, 0, stream>>>(Qb, Kb, Vtb, attn, ctxb);
    o_proj<<<dim3(256), blk, 0, stream>>>(ctxb, wob, Wo_b, out);
}